// Round 1
// baseline (1172.274 us; speedup 1.0000x reference)
//
#include <hip/hip_runtime.h>

#define N_  100000
#define F_  5
#define D_  128
#define H_  4
#define HD_ 32
#define E_  800000
#define NT_ 32

// ---------------------------------------------------------------------------
// Generic tiled GEMM: Y[n, m] = act( X[n, :] @ W[:, m] + bias[m] ) (+ Res)
// Block: 128 threads, NT_=32 nodes. Each thread owns 4 output features and
// NPT nodes in registers. X staged transposed in LDS with stride 33 (pad +1).
// W staged in <=32KB LDS tiles (KT=64 rows max).
// ---------------------------------------------------------------------------
template<int K, int M, bool RELU, bool RES>
__global__ __launch_bounds__(128) void gemm_kernel(
    const float* __restrict__ X, const float* __restrict__ W,
    const float* __restrict__ bias, const float* __restrict__ Res,
    float* __restrict__ Y)
{
  constexpr int FG  = M / 4;        // feature groups (32 for M=128, 16 for M=64)
  constexpr int NG  = 128 / FG;     // node groups
  constexpr int NPT = NT_ / NG;     // nodes per thread (8 or 4)
  constexpr int KT  = (K > 64) ? 64 : K;

  __shared__ float sxT[K * 33];     // X tile, transposed, padded stride 33
  __shared__ float sw[KT * M];      // W tile
  __shared__ float sb[M];

  const int t = threadIdx.x;
  const long node0 = (long)blockIdx.x * NT_;

  // stage X tile (transposed)
  for (int i = t; i < NT_ * K; i += 128) {
    int n = i / K, k = i % K;
    sxT[k * 33 + n] = X[(node0 + n) * K + k];
  }
  if (t < M) sb[t] = bias[t];
  __syncthreads();

  const int tf = t % FG;
  const int tn = t / FG;
  float acc[NPT][4];
  #pragma unroll
  for (int n = 0; n < NPT; ++n) {
    #pragma unroll
    for (int f = 0; f < 4; ++f) acc[n][f] = sb[tf * 4 + f];
  }

  for (int kt = 0; kt < K; kt += KT) {
    for (int i = t; i < KT * M; i += 128) sw[i] = W[kt * M + i];
    __syncthreads();
    #pragma unroll 8
    for (int j = 0; j < KT; ++j) {
      const float4 wv = *(const float4*)&sw[j * M + tf * 4];
      #pragma unroll
      for (int n = 0; n < NPT; ++n) {
        const float xv = sxT[(kt + j) * 33 + tn * NPT + n];
        acc[n][0] = fmaf(xv, wv.x, acc[n][0]);
        acc[n][1] = fmaf(xv, wv.y, acc[n][1]);
        acc[n][2] = fmaf(xv, wv.z, acc[n][2]);
        acc[n][3] = fmaf(xv, wv.w, acc[n][3]);
      }
    }
    __syncthreads();
  }

  #pragma unroll
  for (int n = 0; n < NPT; ++n) {
    const long row = node0 + tn * NPT + n;
    float4 o = make_float4(acc[n][0], acc[n][1], acc[n][2], acc[n][3]);
    if constexpr (RELU) {
      o.x = fmaxf(o.x, 0.f); o.y = fmaxf(o.y, 0.f);
      o.z = fmaxf(o.z, 0.f); o.w = fmaxf(o.w, 0.f);
    }
    if constexpr (RES) {
      const float4 r = *(const float4*)&Res[row * M + tf * 4];
      o.x += r.x; o.y += r.y; o.z += r.z; o.w += r.w;
    }
    *(float4*)&Y[row * M + tf * 4] = o;
  }
}

// ---------------------------------------------------------------------------
// Edge-phase kernels
// ---------------------------------------------------------------------------
__device__ __forceinline__ unsigned float_ord(float f) {
  unsigned b = __float_as_uint(f);
  return (b & 0x80000000u) ? ~b : (b | 0x80000000u);
}
__device__ __forceinline__ float ord_float(unsigned u) {
  return (u & 0x80000000u) ? __uint_as_float(u ^ 0x80000000u)
                           : __uint_as_float(~u);
}

__global__ __launch_bounds__(256) void k_init_md(unsigned* __restrict__ m_ord,
                                                 float* __restrict__ denom) {
  int i = blockIdx.x * 256 + threadIdx.x;
  if (i < N_ * H_) {
    m_ord[i] = float_ord(-__builtin_inff());  // == 0x007FFFFF
    denom[i] = 0.f;
  }
}

// score[e,h] = scale * dot(q[dst,h,:], k[src,h,:]); atomicMax into m_ord
__global__ __launch_bounds__(256) void k_score(
    const int* __restrict__ ei, const float* __restrict__ q,
    const float* __restrict__ kk, float* __restrict__ score,
    unsigned* __restrict__ m_ord)
{
  int tid = blockIdx.x * 256 + threadIdx.x;
  if (tid >= E_ * H_) return;
  int e = tid >> 2, h = tid & 3;
  int src = ei[e], dst = ei[E_ + e];
  const float4* q4 = (const float4*)(q  + (long)dst * D_ + h * HD_);
  const float4* k4 = (const float4*)(kk + (long)src * D_ + h * HD_);
  float acc = 0.f;
  #pragma unroll
  for (int d = 0; d < HD_ / 4; ++d) {
    float4 a = q4[d], b = k4[d];
    acc += a.x * b.x + a.y * b.y + a.z * b.z + a.w * b.w;
  }
  float s = acc * 0.17677669529663687f;  // 1/sqrt(32)
  score[tid] = s;
  atomicMax(&m_ord[dst * H_ + h], float_ord(s));
}

// e = exp(score - m[dst]); overwrite score with e; atomicAdd into denom
__global__ __launch_bounds__(256) void k_expsum(
    const int* __restrict__ ei, float* __restrict__ score,
    const unsigned* __restrict__ m_ord, float* __restrict__ denom)
{
  int tid = blockIdx.x * 256 + threadIdx.x;
  if (tid >= E_ * H_) return;
  int e = tid >> 2, h = tid & 3;
  int dst = ei[E_ + e];
  float m = ord_float(m_ord[dst * H_ + h]);
  float ex = expf(score[tid] - m);
  score[tid] = ex;
  atomicAdd(&denom[dst * H_ + h], ex);
}

// agg[dst, d] += (e/denom) * v[src, d]   (one thread per edge-channel)
__global__ __launch_bounds__(256) void k_agg(
    const int* __restrict__ ei, const float* __restrict__ escore,
    const float* __restrict__ denom, const float* __restrict__ v,
    float* __restrict__ agg)
{
  int tid = blockIdx.x * 256 + threadIdx.x;
  if (tid >= E_ * D_ ? 0 : 1) {
    int e = tid >> 7;
    int d = tid & 127;
    int h = d >> 5;
    int src = ei[e], dst = ei[E_ + e];
    float alpha = escore[e * H_ + h] / denom[dst * H_ + h];
    atomicAdd(&agg[(long)dst * D_ + d], alpha * v[(long)src * D_ + d]);
  }
}

// ---------------------------------------------------------------------------
extern "C" void kernel_launch(void* const* d_in, const int* in_sizes, int n_in,
                              void* d_out, int out_size, void* d_ws, size_t ws_size,
                              hipStream_t stream) {
  const float* x   = (const float*)d_in[0];
  const int*   ei  = (const int*)d_in[1];
  const float* pW1 = (const float*)d_in[2];  const float* pb1 = (const float*)d_in[3];
  const float* pW2 = (const float*)d_in[4];  const float* pb2 = (const float*)d_in[5];
  const float* pW3 = (const float*)d_in[6];  const float* pb3 = (const float*)d_in[7];
  const float* uW1 = (const float*)d_in[8];  const float* ub1 = (const float*)d_in[9];
  const float* uW2 = (const float*)d_in[10]; const float* ub2 = (const float*)d_in[11];
  const float* uW3 = (const float*)d_in[12]; const float* ub3 = (const float*)d_in[13];
  const float* qW  = (const float*)d_in[14]; const float* qb  = (const float*)d_in[15];
  const float* kW  = (const float*)d_in[16]; const float* kb  = (const float*)d_in[17];
  const float* vW  = (const float*)d_in[18]; const float* vb  = (const float*)d_in[19];
  const float* sW  = (const float*)d_in[20]; const float* sb  = (const float*)d_in[21];

  float* out = (float*)d_out;
  float* ws  = (float*)d_ws;

  const long ND = (long)N_ * D_;           // 12.8M floats per region
  float* h_init = ws;                       // region 0
  float* qbuf   = ws + ND;                  // region 1
  float* kbuf   = ws + 2 * ND;              // region 2
  float* vbuf   = ws + 3 * ND;              // region 3

  // overlays (region 0 is dead after the projections):
  float*    score = h_init;                                   // E*H
  unsigned* m_ord = (unsigned*)(h_init + (long)E_ * H_);      // N*H
  float*    denom = h_init + (long)E_ * H_ + (long)N_ * H_;   // N*H
  // overlays for the update-MLP (regions 1/2 dead after k_score):
  float* t1 = kbuf;   // N x 64 temporaries
  float* t2 = qbuf;   // N x 128 temporaries

  const int gN = N_ / NT_;  // 3125

  // --- prep MLP: x -> h_init ---
  gemm_kernel<F_, 64, true,  false><<<gN, 128, 0, stream>>>(x,  pW1, pb1, nullptr, t1);
  gemm_kernel<64, 128, true, false><<<gN, 128, 0, stream>>>(t1, pW2, pb2, nullptr, t2);
  gemm_kernel<128,128, false,false><<<gN, 128, 0, stream>>>(t2, pW3, pb3, nullptr, h_init);

  // --- projections ---
  gemm_kernel<128,128, false,false><<<gN, 128, 0, stream>>>(h_init, qW, qb, nullptr, qbuf);
  gemm_kernel<128,128, false,false><<<gN, 128, 0, stream>>>(h_init, kW, kb, nullptr, kbuf);
  gemm_kernel<128,128, false,false><<<gN, 128, 0, stream>>>(h_init, vW, vb, nullptr, vbuf);
  // skip projection written straight into d_out == attention accumulator init
  gemm_kernel<128,128, false,false><<<gN, 128, 0, stream>>>(h_init, sW, sb, nullptr, out);

  // --- attention ---
  k_init_md<<<(N_ * H_ + 255) / 256, 256, 0, stream>>>(m_ord, denom);
  k_score  <<<(E_ * H_) / 256, 256, 0, stream>>>(ei, qbuf, kbuf, score, m_ord);
  k_expsum <<<(E_ * H_) / 256, 256, 0, stream>>>(ei, score, m_ord, denom);
  k_agg    <<<(E_ * D_) / 256, 256, 0, stream>>>(ei, score, denom, vbuf, out);

  // --- update MLP with residual: out = h + mlp(h), h == out ---
  gemm_kernel<128, 64, true, false><<<gN, 128, 0, stream>>>(out, uW1, ub1, nullptr, t1);
  gemm_kernel<64, 128, true, false><<<gN, 128, 0, stream>>>(t1,  uW2, ub2, nullptr, t2);
  gemm_kernel<128,128, false,true ><<<gN, 128, 0, stream>>>(t2,  uW3, ub3, out, out);
}

// Round 2
// 1113.831 us; speedup vs baseline: 1.0525x; 1.0525x over previous
//
#include <hip/hip_runtime.h>

#define N_  100000
#define F_  5
#define D_  128
#define H_  4
#define HD_ 32
#define E_  800000
#define NT_ 32

// ---------------------------------------------------------------------------
// Generic tiled GEMM: Y[n, m] = act( X[n, :] @ W[:, m] + bias[m] ) (+ Res)
// ---------------------------------------------------------------------------
template<int K, int M, bool RELU, bool RES>
__global__ __launch_bounds__(128) void gemm_kernel(
    const float* __restrict__ X, const float* __restrict__ W,
    const float* __restrict__ bias, const float* __restrict__ Res,
    float* __restrict__ Y)
{
  constexpr int FG  = M / 4;
  constexpr int NG  = 128 / FG;
  constexpr int NPT = NT_ / NG;
  constexpr int KT  = (K > 64) ? 64 : K;

  __shared__ float sxT[K * 33];
  __shared__ float sw[KT * M];
  __shared__ float sb[M];

  const int t = threadIdx.x;
  const long node0 = (long)blockIdx.x * NT_;

  for (int i = t; i < NT_ * K; i += 128) {
    int n = i / K, k = i % K;
    sxT[k * 33 + n] = X[(node0 + n) * K + k];
  }
  if (t < M) sb[t] = bias[t];
  __syncthreads();

  const int tf = t % FG;
  const int tn = t / FG;
  float acc[NPT][4];
  #pragma unroll
  for (int n = 0; n < NPT; ++n) {
    #pragma unroll
    for (int f = 0; f < 4; ++f) acc[n][f] = sb[tf * 4 + f];
  }

  for (int kt = 0; kt < K; kt += KT) {
    for (int i = t; i < KT * M; i += 128) sw[i] = W[kt * M + i];
    __syncthreads();
    #pragma unroll 8
    for (int j = 0; j < KT; ++j) {
      const float4 wv = *(const float4*)&sw[j * M + tf * 4];
      #pragma unroll
      for (int n = 0; n < NPT; ++n) {
        const float xv = sxT[(kt + j) * 33 + tn * NPT + n];
        acc[n][0] = fmaf(xv, wv.x, acc[n][0]);
        acc[n][1] = fmaf(xv, wv.y, acc[n][1]);
        acc[n][2] = fmaf(xv, wv.z, acc[n][2]);
        acc[n][3] = fmaf(xv, wv.w, acc[n][3]);
      }
    }
    __syncthreads();
  }

  #pragma unroll
  for (int n = 0; n < NPT; ++n) {
    const long row = node0 + tn * NPT + n;
    float4 o = make_float4(acc[n][0], acc[n][1], acc[n][2], acc[n][3]);
    if constexpr (RELU) {
      o.x = fmaxf(o.x, 0.f); o.y = fmaxf(o.y, 0.f);
      o.z = fmaxf(o.z, 0.f); o.w = fmaxf(o.w, 0.f);
    }
    if constexpr (RES) {
      const float4 r = *(const float4*)&Res[row * M + tf * 4];
      o.x += r.x; o.y += r.y; o.z += r.z; o.w += r.w;
    }
    *(float4*)&Y[row * M + tf * 4] = o;
  }
}

// ---------------------------------------------------------------------------
// CSR build: histogram -> scan -> fill
// ---------------------------------------------------------------------------
__global__ __launch_bounds__(256) void k_zero(int* __restrict__ deg) {
  int i = blockIdx.x * 256 + threadIdx.x;
  if (i < N_) deg[i] = 0;
}

__global__ __launch_bounds__(256) void k_hist(const int* __restrict__ ei,
                                              int* __restrict__ deg) {
  int e = blockIdx.x * 256 + threadIdx.x;
  if (e < E_) atomicAdd(&deg[ei[E_ + e]], 1);
}

// single-block scan: 1024 threads, each owns a contiguous chunk
__global__ __launch_bounds__(1024) void k_scan(const int* __restrict__ deg,
                                               int* __restrict__ off,
                                               int* __restrict__ cur) {
  __shared__ int part[1024];
  const int t = threadIdx.x;
  const int CH = (N_ + 1023) / 1024;  // 98
  const int base = t * CH;
  int s = 0;
  for (int i = 0; i < CH; ++i) {
    int idx = base + i;
    if (idx < N_) s += deg[idx];
  }
  part[t] = s;
  __syncthreads();
  for (int o = 1; o < 1024; o <<= 1) {
    int v2 = (t >= o) ? part[t - o] : 0;
    __syncthreads();
    part[t] += v2;
    __syncthreads();
  }
  int run = (t == 0) ? 0 : part[t - 1];
  for (int i = 0; i < CH; ++i) {
    int idx = base + i;
    if (idx < N_) {
      off[idx] = run;
      cur[idx] = run;
      run += deg[idx];
    }
  }
}

__global__ __launch_bounds__(256) void k_fill(const int* __restrict__ ei,
                                              int* __restrict__ cur,
                                              int* __restrict__ esrc) {
  int e = blockIdx.x * 256 + threadIdx.x;
  if (e < E_) {
    int src = ei[e], dst = ei[E_ + e];
    int pos = atomicAdd(&cur[dst], 1);
    esrc[pos] = src;
  }
}

// ---------------------------------------------------------------------------
// Flash-style attention aggregation: one 64-lane wave per destination node.
// Lane owns channels (lane) and (lane+64). Heads: lane>>5 and 2+(lane>>5).
// out already holds the skip projection; we add agg on top.
// ---------------------------------------------------------------------------
__global__ __launch_bounds__(256) void k_attn(
    const int* __restrict__ esrc, const int* __restrict__ off,
    const int* __restrict__ deg, const float* __restrict__ q,
    const float* __restrict__ kbuf, const float* __restrict__ vbuf,
    float* __restrict__ out)
{
  const int node = blockIdx.x * 4 + (threadIdx.x >> 6);
  const int lane = threadIdx.x & 63;
  if (node >= N_) return;

  const int start = off[node];
  const int cnt   = deg[node];
  const float scale = 0.17677669529663687f;  // 1/sqrt(32)

  const float q0 = q[(long)node * D_ + lane] * scale;
  const float q1 = q[(long)node * D_ + lane + 64] * scale;

  float m0 = -__builtin_inff(), l0 = 0.f, a0 = 0.f;
  float m1 = -__builtin_inff(), l1 = 0.f, a1 = 0.f;

  for (int i = 0; i < cnt; ++i) {
    const int src = esrc[start + i];
    const float k0 = kbuf[(long)src * D_ + lane];
    const float k1 = kbuf[(long)src * D_ + lane + 64];
    const float v0 = vbuf[(long)src * D_ + lane];
    const float v1 = vbuf[(long)src * D_ + lane + 64];

    float p0 = q0 * k0;
    float p1 = q1 * k1;
    // reduce within 32-lane halves (heads are 32 channels each)
    #pragma unroll
    for (int msk = 16; msk >= 1; msk >>= 1) {
      p0 += __shfl_xor(p0, msk);
      p1 += __shfl_xor(p1, msk);
    }
    // p0 = score for head (lane>>5); p1 = score for head 2+(lane>>5)

    float m0n = fmaxf(m0, p0);
    float sc0 = __expf(m0 - m0n);
    float e0  = __expf(p0 - m0n);
    l0 = l0 * sc0 + e0;
    a0 = a0 * sc0 + e0 * v0;
    m0 = m0n;

    float m1n = fmaxf(m1, p1);
    float sc1 = __expf(m1 - m1n);
    float e1  = __expf(p1 - m1n);
    l1 = l1 * sc1 + e1;
    a1 = a1 * sc1 + e1 * v1;
    m1 = m1n;
  }

  const float r0 = (l0 > 0.f) ? a0 / l0 : 0.f;
  const float r1 = (l1 > 0.f) ? a1 / l1 : 0.f;
  out[(long)node * D_ + lane]      += r0;
  out[(long)node * D_ + lane + 64] += r1;
}

// ---------------------------------------------------------------------------
extern "C" void kernel_launch(void* const* d_in, const int* in_sizes, int n_in,
                              void* d_out, int out_size, void* d_ws, size_t ws_size,
                              hipStream_t stream) {
  const float* x   = (const float*)d_in[0];
  const int*   ei  = (const int*)d_in[1];
  const float* pW1 = (const float*)d_in[2];  const float* pb1 = (const float*)d_in[3];
  const float* pW2 = (const float*)d_in[4];  const float* pb2 = (const float*)d_in[5];
  const float* pW3 = (const float*)d_in[6];  const float* pb3 = (const float*)d_in[7];
  const float* uW1 = (const float*)d_in[8];  const float* ub1 = (const float*)d_in[9];
  const float* uW2 = (const float*)d_in[10]; const float* ub2 = (const float*)d_in[11];
  const float* uW3 = (const float*)d_in[12]; const float* ub3 = (const float*)d_in[13];
  const float* qW  = (const float*)d_in[14]; const float* qb  = (const float*)d_in[15];
  const float* kW  = (const float*)d_in[16]; const float* kb  = (const float*)d_in[17];
  const float* vW  = (const float*)d_in[18]; const float* vb  = (const float*)d_in[19];
  const float* sW  = (const float*)d_in[20]; const float* sb  = (const float*)d_in[21];

  float* out = (float*)d_out;
  float* ws  = (float*)d_ws;

  const long ND = (long)N_ * D_;
  float* h_init = ws;           // region 0
  float* qbuf   = ws + ND;      // region 1
  float* kbuf   = ws + 2 * ND;  // region 2
  float* vbuf   = ws + 3 * ND;  // region 3

  // CSR overlays in region 0 (h_init dead after the projections)
  int* deg  = (int*)h_init;       // N
  int* off  = deg + N_;           // N
  int* cur  = off + N_;           // N
  int* esrc = cur + N_;           // E

  // update-MLP temporaries (regions 1/2 dead after k_attn)
  float* t1 = kbuf;
  float* t2 = qbuf;

  const int gN = N_ / NT_;  // 3125

  // --- prep MLP: x -> h_init ---
  gemm_kernel<F_, 64, true,  false><<<gN, 128, 0, stream>>>(x,  pW1, pb1, nullptr, t1);
  gemm_kernel<64, 128, true, false><<<gN, 128, 0, stream>>>(t1, pW2, pb2, nullptr, t2);
  gemm_kernel<128,128, false,false><<<gN, 128, 0, stream>>>(t2, pW3, pb3, nullptr, h_init);

  // --- projections ---
  gemm_kernel<128,128, false,false><<<gN, 128, 0, stream>>>(h_init, qW, qb, nullptr, qbuf);
  gemm_kernel<128,128, false,false><<<gN, 128, 0, stream>>>(h_init, kW, kb, nullptr, kbuf);
  gemm_kernel<128,128, false,false><<<gN, 128, 0, stream>>>(h_init, vW, vb, nullptr, vbuf);
  gemm_kernel<128,128, false,false><<<gN, 128, 0, stream>>>(h_init, sW, sb, nullptr, out);

  // --- CSR build (region 0 now free) ---
  k_zero<<<(N_ + 255) / 256, 256, 0, stream>>>(deg);
  k_hist<<<(E_ + 255) / 256, 256, 0, stream>>>(ei, deg);
  k_scan<<<1, 1024, 0, stream>>>(deg, off, cur);
  k_fill<<<(E_ + 255) / 256, 256, 0, stream>>>(ei, cur, esrc);

  // --- attention (adds onto skip already in out) ---
  k_attn<<<(N_ + 3) / 4, 256, 0, stream>>>(esrc, off, deg, qbuf, kbuf, vbuf, out);

  // --- update MLP with residual: out = h + mlp(h), h == out ---
  gemm_kernel<128, 64, true, false><<<gN, 128, 0, stream>>>(out, uW1, ub1, nullptr, t1);
  gemm_kernel<64, 128, true, false><<<gN, 128, 0, stream>>>(t1,  uW2, ub2, nullptr, t2);
  gemm_kernel<128,128, false,true ><<<gN, 128, 0, stream>>>(t2,  uW3, ub3, out, out);
}

// Round 3
// 858.548 us; speedup vs baseline: 1.3654x; 1.2973x over previous
//
#include <hip/hip_runtime.h>

#define N_  100000
#define F_  5
#define D_  128
#define H_  4
#define HD_ 32
#define E_  800000
#define NT_ 32

// ---------------------------------------------------------------------------
// Generic tiled GEMM: Y[n, m] = act( X[n, :] @ W[:, m] + bias[m] ) (+ Res)
// ---------------------------------------------------------------------------
template<int K, int M, bool RELU, bool RES>
__global__ __launch_bounds__(128) void gemm_kernel(
    const float* __restrict__ X, const float* __restrict__ W,
    const float* __restrict__ bias, const float* __restrict__ Res,
    float* __restrict__ Y)
{
  constexpr int FG  = M / 4;
  constexpr int NG  = 128 / FG;
  constexpr int NPT = NT_ / NG;
  constexpr int KT  = (K > 64) ? 64 : K;

  __shared__ float sxT[K * 33];
  __shared__ float sw[KT * M];
  __shared__ float sb[M];

  const int t = threadIdx.x;
  const long node0 = (long)blockIdx.x * NT_;

  for (int i = t; i < NT_ * K; i += 128) {
    int n = i / K, k = i % K;
    sxT[k * 33 + n] = X[(node0 + n) * K + k];
  }
  if (t < M) sb[t] = bias[t];
  __syncthreads();

  const int tf = t % FG;
  const int tn = t / FG;
  float acc[NPT][4];
  #pragma unroll
  for (int n = 0; n < NPT; ++n) {
    #pragma unroll
    for (int f = 0; f < 4; ++f) acc[n][f] = sb[tf * 4 + f];
  }

  for (int kt = 0; kt < K; kt += KT) {
    for (int i = t; i < KT * M; i += 128) sw[i] = W[kt * M + i];
    __syncthreads();
    #pragma unroll 8
    for (int j = 0; j < KT; ++j) {
      const float4 wv = *(const float4*)&sw[j * M + tf * 4];
      #pragma unroll
      for (int n = 0; n < NPT; ++n) {
        const float xv = sxT[(kt + j) * 33 + tn * NPT + n];
        acc[n][0] = fmaf(xv, wv.x, acc[n][0]);
        acc[n][1] = fmaf(xv, wv.y, acc[n][1]);
        acc[n][2] = fmaf(xv, wv.z, acc[n][2]);
        acc[n][3] = fmaf(xv, wv.w, acc[n][3]);
      }
    }
    __syncthreads();
  }

  #pragma unroll
  for (int n = 0; n < NPT; ++n) {
    const long row = node0 + tn * NPT + n;
    float4 o = make_float4(acc[n][0], acc[n][1], acc[n][2], acc[n][3]);
    if constexpr (RELU) {
      o.x = fmaxf(o.x, 0.f); o.y = fmaxf(o.y, 0.f);
      o.z = fmaxf(o.z, 0.f); o.w = fmaxf(o.w, 0.f);
    }
    if constexpr (RES) {
      const float4 r = *(const float4*)&Res[row * M + tf * 4];
      o.x += r.x; o.y += r.y; o.z += r.z; o.w += r.w;
    }
    *(float4*)&Y[row * M + tf * 4] = o;
  }
}

// ---------------------------------------------------------------------------
// CSR build: histogram -> hierarchical scan -> fill
// ---------------------------------------------------------------------------
#define SCAN_NB ((N_ + 255) / 256)   // 391

__global__ __launch_bounds__(256) void k_zero(int* __restrict__ deg) {
  int i = blockIdx.x * 256 + threadIdx.x;
  if (i < N_) deg[i] = 0;
}

__global__ __launch_bounds__(256) void k_hist(const int* __restrict__ ei,
                                              int* __restrict__ deg) {
  int e = blockIdx.x * 256 + threadIdx.x;
  if (e < E_) atomicAdd(&deg[ei[E_ + e]], 1);
}

// level 1: per-256-tile exclusive scan + block sums
__global__ __launch_bounds__(256) void k_scan1(const int* __restrict__ deg,
                                               int* __restrict__ off,
                                               int* __restrict__ bsum) {
  __shared__ int s[256];
  const int t = threadIdx.x;
  const int i = blockIdx.x * 256 + t;
  const int v = (i < N_) ? deg[i] : 0;
  s[t] = v;
  __syncthreads();
  #pragma unroll
  for (int o = 1; o < 256; o <<= 1) {
    int u = (t >= o) ? s[t - o] : 0;
    __syncthreads();
    s[t] += u;
    __syncthreads();
  }
  if (i < N_) off[i] = s[t] - v;          // exclusive within tile
  if (t == 255) bsum[blockIdx.x] = s[255];
}

// level 2: single-block exclusive scan of the 391 block sums
__global__ __launch_bounds__(512) void k_scan2(int* __restrict__ bsum) {
  __shared__ int s[512];
  const int t = threadIdx.x;
  const int v = (t < SCAN_NB) ? bsum[t] : 0;
  s[t] = v;
  __syncthreads();
  #pragma unroll
  for (int o = 1; o < 512; o <<= 1) {
    int u = (t >= o) ? s[t - o] : 0;
    __syncthreads();
    s[t] += u;
    __syncthreads();
  }
  if (t < SCAN_NB) bsum[t] = s[t] - v;    // exclusive
}

// level 3: add block offsets, produce off and cur
__global__ __launch_bounds__(256) void k_scan3(int* __restrict__ off,
                                               const int* __restrict__ bsum,
                                               int* __restrict__ cur) {
  const int i = blockIdx.x * 256 + threadIdx.x;
  if (i < N_) {
    const int o = off[i] + bsum[blockIdx.x];
    off[i] = o;
    cur[i] = o;
  }
}

__global__ __launch_bounds__(256) void k_fill(const int* __restrict__ ei,
                                              int* __restrict__ cur,
                                              int* __restrict__ esrc) {
  int e = blockIdx.x * 256 + threadIdx.x;
  if (e < E_) {
    int src = ei[e], dst = ei[E_ + e];
    int pos = atomicAdd(&cur[dst], 1);
    esrc[pos] = src;
  }
}

// ---------------------------------------------------------------------------
// Flash-style attention aggregation: one 64-lane wave per destination node.
// Lane owns channels (lane) and (lane+64). Heads: lane>>5 and 2+(lane>>5).
// out already holds the skip projection; we add agg on top.
// ---------------------------------------------------------------------------
__global__ __launch_bounds__(256) void k_attn(
    const int* __restrict__ esrc, const int* __restrict__ off,
    const int* __restrict__ deg, const float* __restrict__ q,
    const float* __restrict__ kbuf, const float* __restrict__ vbuf,
    float* __restrict__ out)
{
  const int node = blockIdx.x * 4 + (threadIdx.x >> 6);
  const int lane = threadIdx.x & 63;
  if (node >= N_) return;

  const int start = off[node];
  const int cnt   = deg[node];
  const float scale = 0.17677669529663687f;  // 1/sqrt(32)

  const float q0 = q[(long)node * D_ + lane] * scale;
  const float q1 = q[(long)node * D_ + lane + 64] * scale;

  float m0 = -__builtin_inff(), l0 = 0.f, a0 = 0.f;
  float m1 = -__builtin_inff(), l1 = 0.f, a1 = 0.f;

  for (int i = 0; i < cnt; ++i) {
    const int src = esrc[start + i];
    const float k0 = kbuf[(long)src * D_ + lane];
    const float k1 = kbuf[(long)src * D_ + lane + 64];
    const float v0 = vbuf[(long)src * D_ + lane];
    const float v1 = vbuf[(long)src * D_ + lane + 64];

    float p0 = q0 * k0;
    float p1 = q1 * k1;
    #pragma unroll
    for (int msk = 16; msk >= 1; msk >>= 1) {
      p0 += __shfl_xor(p0, msk);
      p1 += __shfl_xor(p1, msk);
    }

    float m0n = fmaxf(m0, p0);
    float sc0 = __expf(m0 - m0n);
    float e0  = __expf(p0 - m0n);
    l0 = l0 * sc0 + e0;
    a0 = a0 * sc0 + e0 * v0;
    m0 = m0n;

    float m1n = fmaxf(m1, p1);
    float sc1 = __expf(m1 - m1n);
    float e1  = __expf(p1 - m1n);
    l1 = l1 * sc1 + e1;
    a1 = a1 * sc1 + e1 * v1;
    m1 = m1n;
  }

  const float r0 = (l0 > 0.f) ? a0 / l0 : 0.f;
  const float r1 = (l1 > 0.f) ? a1 / l1 : 0.f;
  out[(long)node * D_ + lane]      += r0;
  out[(long)node * D_ + lane + 64] += r1;
}

// ---------------------------------------------------------------------------
extern "C" void kernel_launch(void* const* d_in, const int* in_sizes, int n_in,
                              void* d_out, int out_size, void* d_ws, size_t ws_size,
                              hipStream_t stream) {
  const float* x   = (const float*)d_in[0];
  const int*   ei  = (const int*)d_in[1];
  const float* pW1 = (const float*)d_in[2];  const float* pb1 = (const float*)d_in[3];
  const float* pW2 = (const float*)d_in[4];  const float* pb2 = (const float*)d_in[5];
  const float* pW3 = (const float*)d_in[6];  const float* pb3 = (const float*)d_in[7];
  const float* uW1 = (const float*)d_in[8];  const float* ub1 = (const float*)d_in[9];
  const float* uW2 = (const float*)d_in[10]; const float* ub2 = (const float*)d_in[11];
  const float* uW3 = (const float*)d_in[12]; const float* ub3 = (const float*)d_in[13];
  const float* qW  = (const float*)d_in[14]; const float* qb  = (const float*)d_in[15];
  const float* kW  = (const float*)d_in[16]; const float* kb  = (const float*)d_in[17];
  const float* vW  = (const float*)d_in[18]; const float* vb  = (const float*)d_in[19];
  const float* sW  = (const float*)d_in[20]; const float* sb  = (const float*)d_in[21];

  float* out = (float*)d_out;
  float* ws  = (float*)d_ws;

  const long ND = (long)N_ * D_;
  float* h_init = ws;           // region 0
  float* qbuf   = ws + ND;      // region 1
  float* kbuf   = ws + 2 * ND;  // region 2
  float* vbuf   = ws + 3 * ND;  // region 3

  // CSR overlays in region 0 (h_init dead after the projections)
  int* deg  = (int*)h_init;       // N
  int* off  = deg + N_;           // N
  int* cur  = off + N_;           // N
  int* esrc = cur + N_;           // E
  int* bsum = esrc + E_;          // SCAN_NB

  // update-MLP temporaries (regions 1/2 dead after k_attn)
  float* t1 = kbuf;
  float* t2 = qbuf;

  const int gN = N_ / NT_;  // 3125

  // --- prep MLP: x -> h_init ---
  gemm_kernel<F_, 64, true,  false><<<gN, 128, 0, stream>>>(x,  pW1, pb1, nullptr, t1);
  gemm_kernel<64, 128, true, false><<<gN, 128, 0, stream>>>(t1, pW2, pb2, nullptr, t2);
  gemm_kernel<128,128, false,false><<<gN, 128, 0, stream>>>(t2, pW3, pb3, nullptr, h_init);

  // --- projections ---
  gemm_kernel<128,128, false,false><<<gN, 128, 0, stream>>>(h_init, qW, qb, nullptr, qbuf);
  gemm_kernel<128,128, false,false><<<gN, 128, 0, stream>>>(h_init, kW, kb, nullptr, kbuf);
  gemm_kernel<128,128, false,false><<<gN, 128, 0, stream>>>(h_init, vW, vb, nullptr, vbuf);
  gemm_kernel<128,128, false,false><<<gN, 128, 0, stream>>>(h_init, sW, sb, nullptr, out);

  // --- CSR build (region 0 now free) ---
  k_zero <<<(N_ + 255) / 256, 256, 0, stream>>>(deg);
  k_hist <<<(E_ + 255) / 256, 256, 0, stream>>>(ei, deg);
  k_scan1<<<SCAN_NB, 256, 0, stream>>>(deg, off, bsum);
  k_scan2<<<1, 512, 0, stream>>>(bsum);
  k_scan3<<<SCAN_NB, 256, 0, stream>>>(off, bsum, cur);
  k_fill <<<(E_ + 255) / 256, 256, 0, stream>>>(ei, cur, esrc);

  // --- attention (adds onto skip already in out) ---
  k_attn<<<(N_ + 3) / 4, 256, 0, stream>>>(esrc, off, deg, qbuf, kbuf, vbuf, out);

  // --- update MLP with residual: out = h + mlp(h), h == out ---
  gemm_kernel<128, 64, true, false><<<gN, 128, 0, stream>>>(out, uW1, ub1, nullptr, t1);
  gemm_kernel<64, 128, true, false><<<gN, 128, 0, stream>>>(t1,  uW2, ub2, nullptr, t2);
  gemm_kernel<128,128, false,true ><<<gN, 128, 0, stream>>>(t2,  uW3, ub3, out, out);
}

// Round 4
// 778.984 us; speedup vs baseline: 1.5049x; 1.1021x over previous
//
#include <hip/hip_runtime.h>

#define N_  100000
#define F_  5
#define D_  128
#define H_  4
#define HD_ 32
#define E_  800000
#define NT_ 32

// ---------------------------------------------------------------------------
// High-intensity GEMM: 256 threads, each owns 8 features x 8 nodes.
// Tile: NT nodes x M features, KT=32 K-tiles.
// LDS strides chosen == 4 (mod 32) floats; wave-local tf/tn span 8 ->
// all inner-loop LDS accesses are <=2-way bank aliased (free).
// ---------------------------------------------------------------------------
template<int K, int M, bool RELU, bool RES>
__global__ __launch_bounds__(256) void gemm8x8(
    const float* __restrict__ X, const float* __restrict__ W,
    const float* __restrict__ bias, const float* __restrict__ Res,
    float* __restrict__ Y)
{
  constexpr int FG  = M / 8;            // 16 (M=128) or 8 (M=64)
  constexpr int NT  = (256 / FG) * 8;   // 128 or 256
  constexpr int KT  = 32;
  constexpr int NTP = NT + 4;           // sxT row stride (floats)
  constexpr int MP  = M + 4;            // sw row stride (floats)
  constexpr bool BIG = (FG == 16);

  __shared__ float sxT[KT * NTP];
  __shared__ float sw[KT * MP];

  const int t = threadIdx.x;
  const int node0 = blockIdx.x * NT;

  // wave-local tf spans 8 values, tn spans 8 values
  const int tf = BIG ? ((t & 7) | ((t >> 7) << 3)) : (t & 7);
  const int tn = BIG ? ((t >> 3) & 15) : (t >> 3);

  // bias -> acc init
  const float4 b0 = ((const float4*)bias)[tf * 2];
  const float4 b1 = ((const float4*)bias)[tf * 2 + 1];
  float acc[8][8];
  #pragma unroll
  for (int n = 0; n < 8; ++n) {
    acc[n][0] = b0.x; acc[n][1] = b0.y; acc[n][2] = b0.z; acc[n][3] = b0.w;
    acc[n][4] = b1.x; acc[n][5] = b1.y; acc[n][6] = b1.z; acc[n][7] = b1.w;
  }

  const int k4  = t & 7;    // k-quad within KT tile
  const int n4b = t >> 3;   // node-quad base (0..31)

  for (int k0 = 0; k0 < K; k0 += KT) {
    __syncthreads();
    // ---- stage X^T (register transpose, b128 writes) ----
    #pragma unroll
    for (int i = 0; i < NT / 128; ++i) {
      const int n4 = n4b + 32 * i;
      float4 r[4];
      #pragma unroll
      for (int r_ = 0; r_ < 4; ++r_) {
        const int n = node0 + n4 * 4 + r_;
        r[r_] = (n < N_) ? *(const float4*)&X[(long)n * K + k0 + k4 * 4]
                         : make_float4(0.f, 0.f, 0.f, 0.f);
      }
      float4* sx4 = (float4*)sxT;
      sx4[(k4 * 4 + 0) * (NTP / 4) + n4] = make_float4(r[0].x, r[1].x, r[2].x, r[3].x);
      sx4[(k4 * 4 + 1) * (NTP / 4) + n4] = make_float4(r[0].y, r[1].y, r[2].y, r[3].y);
      sx4[(k4 * 4 + 2) * (NTP / 4) + n4] = make_float4(r[0].z, r[1].z, r[2].z, r[3].z);
      sx4[(k4 * 4 + 3) * (NTP / 4) + n4] = make_float4(r[0].w, r[1].w, r[2].w, r[3].w);
    }
    // ---- stage W ----
    constexpr int WI = (KT * M / 4) / 256;   // 4 or 2
    #pragma unroll
    for (int i = 0; i < WI; ++i) {
      const int idx = t + 256 * i;
      const int j  = idx / (M / 4);
      const int f4 = idx % (M / 4);
      ((float4*)sw)[j * (MP / 4) + f4] = ((const float4*)W)[(long)(k0 + j) * (M / 4) + f4];
    }
    __syncthreads();
    // ---- inner: 64 FMA per j per thread ----
    #pragma unroll 4
    for (int j = 0; j < KT; ++j) {
      const float4 xa = ((const float4*)sxT)[j * (NTP / 4) + tn * 2];
      const float4 xb = ((const float4*)sxT)[j * (NTP / 4) + tn * 2 + 1];
      const float4 wa = ((const float4*)sw)[j * (MP / 4) + tf * 2];
      const float4 wb = ((const float4*)sw)[j * (MP / 4) + tf * 2 + 1];
      const float xr[8] = {xa.x, xa.y, xa.z, xa.w, xb.x, xb.y, xb.z, xb.w};
      const float wr[8] = {wa.x, wa.y, wa.z, wa.w, wb.x, wb.y, wb.z, wb.w};
      #pragma unroll
      for (int n = 0; n < 8; ++n)
        #pragma unroll
        for (int f = 0; f < 8; ++f)
          acc[n][f] = fmaf(xr[n], wr[f], acc[n][f]);
    }
  }

  // ---- epilogue ----
  #pragma unroll
  for (int n = 0; n < 8; ++n) {
    const int row = node0 + tn * 8 + n;
    if (row >= N_) continue;
    float4 o0 = make_float4(acc[n][0], acc[n][1], acc[n][2], acc[n][3]);
    float4 o1 = make_float4(acc[n][4], acc[n][5], acc[n][6], acc[n][7]);
    if constexpr (RELU) {
      o0.x = fmaxf(o0.x, 0.f); o0.y = fmaxf(o0.y, 0.f);
      o0.z = fmaxf(o0.z, 0.f); o0.w = fmaxf(o0.w, 0.f);
      o1.x = fmaxf(o1.x, 0.f); o1.y = fmaxf(o1.y, 0.f);
      o1.z = fmaxf(o1.z, 0.f); o1.w = fmaxf(o1.w, 0.f);
    }
    if constexpr (RES) {
      const float4 r0 = ((const float4*)Res)[(long)row * (M / 4) + tf * 2];
      const float4 r1 = ((const float4*)Res)[(long)row * (M / 4) + tf * 2 + 1];
      o0.x += r0.x; o0.y += r0.y; o0.z += r0.z; o0.w += r0.w;
      o1.x += r1.x; o1.y += r1.y; o1.z += r1.z; o1.w += r1.w;
    }
    ((float4*)Y)[(long)row * (M / 4) + tf * 2]     = o0;
    ((float4*)Y)[(long)row * (M / 4) + tf * 2 + 1] = o1;
  }
}

// ---------------------------------------------------------------------------
// Small-K GEMM (K=5): the old 32-node kernel, fine for this shape.
// ---------------------------------------------------------------------------
template<int K, int M, bool RELU>
__global__ __launch_bounds__(128) void gemm_small(
    const float* __restrict__ X, const float* __restrict__ W,
    const float* __restrict__ bias, float* __restrict__ Y)
{
  constexpr int FG  = M / 4;
  constexpr int NG  = 128 / FG;
  constexpr int NPT = NT_ / NG;

  __shared__ float sxT[K * 33];
  __shared__ float sw[K * M];
  __shared__ float sb[M];

  const int t = threadIdx.x;
  const long node0 = (long)blockIdx.x * NT_;

  for (int i = t; i < NT_ * K; i += 128) {
    int n = i / K, k = i % K;
    sxT[k * 33 + n] = X[(node0 + n) * K + k];
  }
  for (int i = t; i < K * M; i += 128) sw[i] = W[i];
  if (t < M) sb[t] = bias[t];
  __syncthreads();

  const int tf = t % FG;
  const int tn = t / FG;
  float acc[NPT][4];
  #pragma unroll
  for (int n = 0; n < NPT; ++n)
    #pragma unroll
    for (int f = 0; f < 4; ++f) acc[n][f] = sb[tf * 4 + f];

  #pragma unroll
  for (int j = 0; j < K; ++j) {
    const float4 wv = *(const float4*)&sw[j * M + tf * 4];
    #pragma unroll
    for (int n = 0; n < NPT; ++n) {
      const float xv = sxT[j * 33 + tn * NPT + n];
      acc[n][0] = fmaf(xv, wv.x, acc[n][0]);
      acc[n][1] = fmaf(xv, wv.y, acc[n][1]);
      acc[n][2] = fmaf(xv, wv.z, acc[n][2]);
      acc[n][3] = fmaf(xv, wv.w, acc[n][3]);
    }
  }

  #pragma unroll
  for (int n = 0; n < NPT; ++n) {
    const long row = node0 + tn * NPT + n;
    float4 o = make_float4(acc[n][0], acc[n][1], acc[n][2], acc[n][3]);
    if constexpr (RELU) {
      o.x = fmaxf(o.x, 0.f); o.y = fmaxf(o.y, 0.f);
      o.z = fmaxf(o.z, 0.f); o.w = fmaxf(o.w, 0.f);
    }
    *(float4*)&Y[row * M + tf * 4] = o;
  }
}

// ---------------------------------------------------------------------------
// CSR build: histogram -> hierarchical scan -> fill
// ---------------------------------------------------------------------------
#define SCAN_NB ((N_ + 255) / 256)   // 391

__global__ __launch_bounds__(256) void k_zero(int* __restrict__ deg) {
  int i = blockIdx.x * 256 + threadIdx.x;
  if (i < N_) deg[i] = 0;
}

__global__ __launch_bounds__(256) void k_hist(const int* __restrict__ ei,
                                              int* __restrict__ deg) {
  int e = blockIdx.x * 256 + threadIdx.x;
  if (e < E_) atomicAdd(&deg[ei[E_ + e]], 1);
}

__global__ __launch_bounds__(256) void k_scan1(const int* __restrict__ deg,
                                               int* __restrict__ off,
                                               int* __restrict__ bsum) {
  __shared__ int s[256];
  const int t = threadIdx.x;
  const int i = blockIdx.x * 256 + t;
  const int v = (i < N_) ? deg[i] : 0;
  s[t] = v;
  __syncthreads();
  #pragma unroll
  for (int o = 1; o < 256; o <<= 1) {
    int u = (t >= o) ? s[t - o] : 0;
    __syncthreads();
    s[t] += u;
    __syncthreads();
  }
  if (i < N_) off[i] = s[t] - v;
  if (t == 255) bsum[blockIdx.x] = s[255];
}

__global__ __launch_bounds__(512) void k_scan2(int* __restrict__ bsum) {
  __shared__ int s[512];
  const int t = threadIdx.x;
  const int v = (t < SCAN_NB) ? bsum[t] : 0;
  s[t] = v;
  __syncthreads();
  #pragma unroll
  for (int o = 1; o < 512; o <<= 1) {
    int u = (t >= o) ? s[t - o] : 0;
    __syncthreads();
    s[t] += u;
    __syncthreads();
  }
  if (t < SCAN_NB) bsum[t] = s[t] - v;
}

__global__ __launch_bounds__(256) void k_scan3(int* __restrict__ off,
                                               const int* __restrict__ bsum,
                                               int* __restrict__ cur) {
  const int i = blockIdx.x * 256 + threadIdx.x;
  if (i < N_) {
    const int o = off[i] + bsum[blockIdx.x];
    off[i] = o;
    cur[i] = o;
  }
}

__global__ __launch_bounds__(256) void k_fill(const int* __restrict__ ei,
                                              int* __restrict__ cur,
                                              int* __restrict__ esrc) {
  int e = blockIdx.x * 256 + threadIdx.x;
  if (e < E_) {
    int src = ei[e], dst = ei[E_ + e];
    int pos = atomicAdd(&cur[dst], 1);
    esrc[pos] = src;
  }
}

// ---------------------------------------------------------------------------
// Flash-style attention aggregation: one wave per destination node.
// ---------------------------------------------------------------------------
__global__ __launch_bounds__(256) void k_attn(
    const int* __restrict__ esrc, const int* __restrict__ off,
    const int* __restrict__ deg, const float* __restrict__ q,
    const float* __restrict__ kbuf, const float* __restrict__ vbuf,
    float* __restrict__ out)
{
  const int node = blockIdx.x * 4 + (threadIdx.x >> 6);
  const int lane = threadIdx.x & 63;
  if (node >= N_) return;

  const int start = off[node];
  const int cnt   = deg[node];
  const float scale = 0.17677669529663687f;  // 1/sqrt(32)

  const float q0 = q[(long)node * D_ + lane] * scale;
  const float q1 = q[(long)node * D_ + lane + 64] * scale;

  float m0 = -__builtin_inff(), l0 = 0.f, a0 = 0.f;
  float m1 = -__builtin_inff(), l1 = 0.f, a1 = 0.f;

  for (int i = 0; i < cnt; ++i) {
    const int src = esrc[start + i];
    const float k0 = kbuf[(long)src * D_ + lane];
    const float k1 = kbuf[(long)src * D_ + lane + 64];
    const float v0 = vbuf[(long)src * D_ + lane];
    const float v1 = vbuf[(long)src * D_ + lane + 64];

    float p0 = q0 * k0;
    float p1 = q1 * k1;
    #pragma unroll
    for (int msk = 16; msk >= 1; msk >>= 1) {
      p0 += __shfl_xor(p0, msk);
      p1 += __shfl_xor(p1, msk);
    }

    float m0n = fmaxf(m0, p0);
    float sc0 = __expf(m0 - m0n);
    float e0  = __expf(p0 - m0n);
    l0 = l0 * sc0 + e0;
    a0 = a0 * sc0 + e0 * v0;
    m0 = m0n;

    float m1n = fmaxf(m1, p1);
    float sc1 = __expf(m1 - m1n);
    float e1  = __expf(p1 - m1n);
    l1 = l1 * sc1 + e1;
    a1 = a1 * sc1 + e1 * v1;
    m1 = m1n;
  }

  const float r0 = (l0 > 0.f) ? a0 / l0 : 0.f;
  const float r1 = (l1 > 0.f) ? a1 / l1 : 0.f;
  out[(long)node * D_ + lane]      += r0;
  out[(long)node * D_ + lane + 64] += r1;
}

// ---------------------------------------------------------------------------
extern "C" void kernel_launch(void* const* d_in, const int* in_sizes, int n_in,
                              void* d_out, int out_size, void* d_ws, size_t ws_size,
                              hipStream_t stream) {
  const float* x   = (const float*)d_in[0];
  const int*   ei  = (const int*)d_in[1];
  const float* pW1 = (const float*)d_in[2];  const float* pb1 = (const float*)d_in[3];
  const float* pW2 = (const float*)d_in[4];  const float* pb2 = (const float*)d_in[5];
  const float* pW3 = (const float*)d_in[6];  const float* pb3 = (const float*)d_in[7];
  const float* uW1 = (const float*)d_in[8];  const float* ub1 = (const float*)d_in[9];
  const float* uW2 = (const float*)d_in[10]; const float* ub2 = (const float*)d_in[11];
  const float* uW3 = (const float*)d_in[12]; const float* ub3 = (const float*)d_in[13];
  const float* qW  = (const float*)d_in[14]; const float* qb  = (const float*)d_in[15];
  const float* kW  = (const float*)d_in[16]; const float* kb  = (const float*)d_in[17];
  const float* vW  = (const float*)d_in[18]; const float* vb  = (const float*)d_in[19];
  const float* sW  = (const float*)d_in[20]; const float* sb  = (const float*)d_in[21];

  float* out = (float*)d_out;
  float* ws  = (float*)d_ws;

  const long ND = (long)N_ * D_;
  float* h_init = ws;           // region 0
  float* qbuf   = ws + ND;      // region 1
  float* kbuf   = ws + 2 * ND;  // region 2
  float* vbuf   = ws + 3 * ND;  // region 3

  // CSR overlays in region 0 (h_init dead after the projections)
  int* deg  = (int*)h_init;
  int* off  = deg + N_;
  int* cur  = off + N_;
  int* esrc = cur + N_;
  int* bsum = esrc + E_;

  // update-MLP temporaries (regions 1/2 dead after k_attn)
  float* t1 = kbuf;
  float* t2 = qbuf;

  const int g32  = N_ / NT_;            // 3125 (for gemm_small)
  const int g128 = (N_ + 127) / 128;    // 782
  const int g256 = (N_ + 255) / 256;    // 391

  // --- prep MLP: x -> h_init ---
  gemm_small<F_, 64, true><<<g32, 128, 0, stream>>>(x, pW1, pb1, t1);
  gemm8x8<64, 128, true,  false><<<g128, 256, 0, stream>>>(t1, pW2, pb2, nullptr, t2);
  gemm8x8<128,128, false, false><<<g128, 256, 0, stream>>>(t2, pW3, pb3, nullptr, h_init);

  // --- projections ---
  gemm8x8<128,128, false, false><<<g128, 256, 0, stream>>>(h_init, qW, qb, nullptr, qbuf);
  gemm8x8<128,128, false, false><<<g128, 256, 0, stream>>>(h_init, kW, kb, nullptr, kbuf);
  gemm8x8<128,128, false, false><<<g128, 256, 0, stream>>>(h_init, vW, vb, nullptr, vbuf);
  gemm8x8<128,128, false, false><<<g128, 256, 0, stream>>>(h_init, sW, sb, nullptr, out);

  // --- CSR build (region 0 now free) ---
  k_zero <<<(N_ + 255) / 256, 256, 0, stream>>>(deg);
  k_hist <<<(E_ + 255) / 256, 256, 0, stream>>>(ei, deg);
  k_scan1<<<SCAN_NB, 256, 0, stream>>>(deg, off, bsum);
  k_scan2<<<1, 512, 0, stream>>>(bsum);
  k_scan3<<<SCAN_NB, 256, 0, stream>>>(off, bsum, cur);
  k_fill <<<(E_ + 255) / 256, 256, 0, stream>>>(ei, cur, esrc);

  // --- attention (adds onto skip already in out) ---
  k_attn<<<(N_ + 3) / 4, 256, 0, stream>>>(esrc, off, deg, qbuf, kbuf, vbuf, out);

  // --- update MLP with residual: out = h + mlp(h), h == out ---
  gemm8x8<128, 64, true,  false><<<g256, 256, 0, stream>>>(out, uW1, ub1, nullptr, t1);
  gemm8x8<64, 128, true,  false><<<g128, 256, 0, stream>>>(t1,  uW2, ub2, nullptr, t2);
  gemm8x8<128,128, false, true ><<<g128, 256, 0, stream>>>(t2,  uW3, ub3, out, out);
}

// Round 5
// 591.244 us; speedup vs baseline: 1.9827x; 1.3175x over previous
//
#include <hip/hip_runtime.h>

#define N_  100000
#define F_  5
#define D_  128
#define H_  4
#define HD_ 32
#define E_  800000
#define NT_ 32

typedef __attribute__((ext_vector_type(8))) short bf16x8;
typedef __attribute__((ext_vector_type(4))) float f32x4;

__device__ __forceinline__ unsigned short f2bf(float f) {
  unsigned u = __float_as_uint(f);
  u += 0x7FFF + ((u >> 16) & 1);          // round-to-nearest-even
  return (unsigned short)(u >> 16);
}

// ---------------------------------------------------------------------------
// bf16 MFMA GEMM: Y[n,m] = act(X[n,:] @ W[:,m] + bias[m]) (+Res), fp32 I/O.
// Tile: 128 nodes x M. 256 threads = 4 waves in 2x2 quadrants (64 x M/2 each).
// W transposed->bf16 in LDS once per block; X tile bf16-staged per 32-k step.
// LDS strides: sA 40 bf16/row, sB K+8 bf16/row -> <=2-way bank aliasing.
// ---------------------------------------------------------------------------
template<int K, int M, bool RELU, bool RES>
__global__ __launch_bounds__(256) void mfma_gemm(
    const float* __restrict__ X, const float* __restrict__ W,
    const float* __restrict__ bias, const float* __restrict__ Res,
    float* __restrict__ Y)
{
  constexpr int SA = 40;            // sA row stride (bf16)
  constexpr int SB = K + 8;         // sB row stride (bf16)
  constexpr int CT = (M / 2) / 16;  // col-tiles per wave (4 or 2)

  __shared__ unsigned short sA[128 * SA];
  __shared__ unsigned short sB[M * SB];
  __shared__ float sBias[M];

  const int t = threadIdx.x;
  const int node0 = blockIdx.x * 128;
  const int lane = t & 63;
  const int w = t >> 6;
  const int wr = w >> 1, wc = w & 1;
  const int l16 = lane & 15, kg = lane >> 4;

  // ---- one-time: W -> sB (transposed, bf16); bias -> sBias ----
  #pragma unroll
  for (int i = 0; i < K * M / 4 / 256; ++i) {
    const int idx = t + 256 * i;
    const int k = idx / (M / 4);
    const int m0 = (idx % (M / 4)) * 4;
    const float4 wv = ((const float4*)W)[idx];
    sB[(m0 + 0) * SB + k] = f2bf(wv.x);
    sB[(m0 + 1) * SB + k] = f2bf(wv.y);
    sB[(m0 + 2) * SB + k] = f2bf(wv.z);
    sB[(m0 + 3) * SB + k] = f2bf(wv.w);
  }
  if (t < M) sBias[t] = bias[t];

  f32x4 acc[4][CT];
  #pragma unroll
  for (int i = 0; i < 4; ++i)
    #pragma unroll
    for (int j = 0; j < CT; ++j)
      acc[i][j] = (f32x4){0.f, 0.f, 0.f, 0.f};

  for (int k0 = 0; k0 < K; k0 += 32) {
    __syncthreads();  // prev readers done (and first-iter sB/bias visible)
    // ---- stage X tile (fp32 -> bf16) ----
    #pragma unroll
    for (int i = 0; i < 2; ++i) {
      const int c = t + 256 * i;
      const int row = c >> 2, kc = c & 3;
      const int g = node0 + row;
      float4 a0, a1;
      if (g < N_) {
        a0 = *(const float4*)&X[(long)g * K + k0 + kc * 8];
        a1 = *(const float4*)&X[(long)g * K + k0 + kc * 8 + 4];
      } else {
        a0 = make_float4(0.f, 0.f, 0.f, 0.f);
        a1 = a0;
      }
      uint4 p;
      p.x = (unsigned)f2bf(a0.x) | ((unsigned)f2bf(a0.y) << 16);
      p.y = (unsigned)f2bf(a0.z) | ((unsigned)f2bf(a0.w) << 16);
      p.z = (unsigned)f2bf(a1.x) | ((unsigned)f2bf(a1.y) << 16);
      p.w = (unsigned)f2bf(a1.z) | ((unsigned)f2bf(a1.w) << 16);
      *(uint4*)&sA[row * SA + kc * 8] = p;
    }
    __syncthreads();
    // ---- MFMA inner ----
    bf16x8 af[4];
    #pragma unroll
    for (int i = 0; i < 4; ++i)
      af[i] = *(const bf16x8*)&sA[(wr * 64 + i * 16 + l16) * SA + kg * 8];
    #pragma unroll
    for (int j = 0; j < CT; ++j) {
      const bf16x8 bfr = *(const bf16x8*)&sB[(wc * (M / 2) + j * 16 + l16) * SB + k0 + kg * 8];
      #pragma unroll
      for (int i = 0; i < 4; ++i)
        acc[i][j] = __builtin_amdgcn_mfma_f32_16x16x32_bf16(af[i], bfr, acc[i][j], 0, 0, 0);
    }
  }

  // ---- epilogue: C/D layout col=lane&15, row=(lane>>4)*4+reg ----
  #pragma unroll
  for (int i = 0; i < 4; ++i) {
    const int rbase = node0 + wr * 64 + i * 16 + kg * 4;
    #pragma unroll
    for (int j = 0; j < CT; ++j) {
      const int col = wc * (M / 2) + j * 16 + l16;
      const float b = sBias[col];
      #pragma unroll
      for (int r = 0; r < 4; ++r) {
        const int g = rbase + r;
        if (g >= N_) continue;
        float v = acc[i][j][r] + b;
        if constexpr (RELU) v = fmaxf(v, 0.f);
        if constexpr (RES) v += Res[(long)g * M + col];
        Y[(long)g * M + col] = v;
      }
    }
  }
}

// ---------------------------------------------------------------------------
// Small-K GEMM (K=5), fp32.
// ---------------------------------------------------------------------------
template<int K, int M, bool RELU>
__global__ __launch_bounds__(128) void gemm_small(
    const float* __restrict__ X, const float* __restrict__ W,
    const float* __restrict__ bias, float* __restrict__ Y)
{
  constexpr int FG  = M / 4;
  constexpr int NG  = 128 / FG;
  constexpr int NPT = NT_ / NG;

  __shared__ float sxT[K * 33];
  __shared__ float sw[K * M];
  __shared__ float sb[M];

  const int t = threadIdx.x;
  const long node0 = (long)blockIdx.x * NT_;

  for (int i = t; i < NT_ * K; i += 128) {
    int n = i / K, k = i % K;
    sxT[k * 33 + n] = X[(node0 + n) * K + k];
  }
  for (int i = t; i < K * M; i += 128) sw[i] = W[i];
  if (t < M) sb[t] = bias[t];
  __syncthreads();

  const int tf = t % FG;
  const int tn = t / FG;
  float acc[NPT][4];
  #pragma unroll
  for (int n = 0; n < NPT; ++n)
    #pragma unroll
    for (int f = 0; f < 4; ++f) acc[n][f] = sb[tf * 4 + f];

  #pragma unroll
  for (int j = 0; j < K; ++j) {
    const float4 wv = *(const float4*)&sw[j * M + tf * 4];
    #pragma unroll
    for (int n = 0; n < NPT; ++n) {
      const float xv = sxT[j * 33 + tn * NPT + n];
      acc[n][0] = fmaf(xv, wv.x, acc[n][0]);
      acc[n][1] = fmaf(xv, wv.y, acc[n][1]);
      acc[n][2] = fmaf(xv, wv.z, acc[n][2]);
      acc[n][3] = fmaf(xv, wv.w, acc[n][3]);
    }
  }

  #pragma unroll
  for (int n = 0; n < NPT; ++n) {
    const long row = node0 + tn * NPT + n;
    float4 o = make_float4(acc[n][0], acc[n][1], acc[n][2], acc[n][3]);
    if constexpr (RELU) {
      o.x = fmaxf(o.x, 0.f); o.y = fmaxf(o.y, 0.f);
      o.z = fmaxf(o.z, 0.f); o.w = fmaxf(o.w, 0.f);
    }
    *(float4*)&Y[row * M + tf * 4] = o;
  }
}

// ---------------------------------------------------------------------------
// CSR build: histogram -> hierarchical scan -> fill
// ---------------------------------------------------------------------------
#define SCAN_NB ((N_ + 255) / 256)   // 391

__global__ __launch_bounds__(256) void k_zero(int* __restrict__ deg) {
  int i = blockIdx.x * 256 + threadIdx.x;
  if (i < N_) deg[i] = 0;
}

__global__ __launch_bounds__(256) void k_hist(const int* __restrict__ ei,
                                              int* __restrict__ deg) {
  int e = blockIdx.x * 256 + threadIdx.x;
  if (e < E_) atomicAdd(&deg[ei[E_ + e]], 1);
}

__global__ __launch_bounds__(256) void k_scan1(const int* __restrict__ deg,
                                               int* __restrict__ off,
                                               int* __restrict__ bsum) {
  __shared__ int s[256];
  const int t = threadIdx.x;
  const int i = blockIdx.x * 256 + t;
  const int v = (i < N_) ? deg[i] : 0;
  s[t] = v;
  __syncthreads();
  #pragma unroll
  for (int o = 1; o < 256; o <<= 1) {
    int u = (t >= o) ? s[t - o] : 0;
    __syncthreads();
    s[t] += u;
    __syncthreads();
  }
  if (i < N_) off[i] = s[t] - v;
  if (t == 255) bsum[blockIdx.x] = s[255];
}

__global__ __launch_bounds__(512) void k_scan2(int* __restrict__ bsum) {
  __shared__ int s[512];
  const int t = threadIdx.x;
  const int v = (t < SCAN_NB) ? bsum[t] : 0;
  s[t] = v;
  __syncthreads();
  #pragma unroll
  for (int o = 1; o < 512; o <<= 1) {
    int u = (t >= o) ? s[t - o] : 0;
    __syncthreads();
    s[t] += u;
    __syncthreads();
  }
  if (t < SCAN_NB) bsum[t] = s[t] - v;
}

__global__ __launch_bounds__(256) void k_scan3(int* __restrict__ off,
                                               const int* __restrict__ bsum,
                                               int* __restrict__ cur) {
  const int i = blockIdx.x * 256 + threadIdx.x;
  if (i < N_) {
    const int o = off[i] + bsum[blockIdx.x];
    off[i] = o;
    cur[i] = o;
  }
}

__global__ __launch_bounds__(256) void k_fill(const int* __restrict__ ei,
                                              int* __restrict__ cur,
                                              int* __restrict__ esrc) {
  int e = blockIdx.x * 256 + threadIdx.x;
  if (e < E_) {
    int src = ei[e], dst = ei[E_ + e];
    int pos = atomicAdd(&cur[dst], 1);
    esrc[pos] = src;
  }
}

// ---------------------------------------------------------------------------
// Flash-style attention aggregation: one wave per destination node.
// ---------------------------------------------------------------------------
__global__ __launch_bounds__(256) void k_attn(
    const int* __restrict__ esrc, const int* __restrict__ off,
    const int* __restrict__ deg, const float* __restrict__ q,
    const float* __restrict__ kbuf, const float* __restrict__ vbuf,
    float* __restrict__ out)
{
  const int node = blockIdx.x * 4 + (threadIdx.x >> 6);
  const int lane = threadIdx.x & 63;
  if (node >= N_) return;

  const int start = off[node];
  const int cnt   = deg[node];
  const float scale = 0.17677669529663687f;  // 1/sqrt(32)

  const float q0 = q[(long)node * D_ + lane] * scale;
  const float q1 = q[(long)node * D_ + lane + 64] * scale;

  float m0 = -__builtin_inff(), l0 = 0.f, a0 = 0.f;
  float m1 = -__builtin_inff(), l1 = 0.f, a1 = 0.f;

  for (int i = 0; i < cnt; ++i) {
    const int src = esrc[start + i];
    const float k0 = kbuf[(long)src * D_ + lane];
    const float k1 = kbuf[(long)src * D_ + lane + 64];
    const float v0 = vbuf[(long)src * D_ + lane];
    const float v1 = vbuf[(long)src * D_ + lane + 64];

    float p0 = q0 * k0;
    float p1 = q1 * k1;
    #pragma unroll
    for (int msk = 16; msk >= 1; msk >>= 1) {
      p0 += __shfl_xor(p0, msk);
      p1 += __shfl_xor(p1, msk);
    }

    float m0n = fmaxf(m0, p0);
    float sc0 = __expf(m0 - m0n);
    float e0  = __expf(p0 - m0n);
    l0 = l0 * sc0 + e0;
    a0 = a0 * sc0 + e0 * v0;
    m0 = m0n;

    float m1n = fmaxf(m1, p1);
    float sc1 = __expf(m1 - m1n);
    float e1  = __expf(p1 - m1n);
    l1 = l1 * sc1 + e1;
    a1 = a1 * sc1 + e1 * v1;
    m1 = m1n;
  }

  const float r0 = (l0 > 0.f) ? a0 / l0 : 0.f;
  const float r1 = (l1 > 0.f) ? a1 / l1 : 0.f;
  out[(long)node * D_ + lane]      += r0;
  out[(long)node * D_ + lane + 64] += r1;
}

// ---------------------------------------------------------------------------
extern "C" void kernel_launch(void* const* d_in, const int* in_sizes, int n_in,
                              void* d_out, int out_size, void* d_ws, size_t ws_size,
                              hipStream_t stream) {
  const float* x   = (const float*)d_in[0];
  const int*   ei  = (const int*)d_in[1];
  const float* pW1 = (const float*)d_in[2];  const float* pb1 = (const float*)d_in[3];
  const float* pW2 = (const float*)d_in[4];  const float* pb2 = (const float*)d_in[5];
  const float* pW3 = (const float*)d_in[6];  const float* pb3 = (const float*)d_in[7];
  const float* uW1 = (const float*)d_in[8];  const float* ub1 = (const float*)d_in[9];
  const float* uW2 = (const float*)d_in[10]; const float* ub2 = (const float*)d_in[11];
  const float* uW3 = (const float*)d_in[12]; const float* ub3 = (const float*)d_in[13];
  const float* qW  = (const float*)d_in[14]; const float* qb  = (const float*)d_in[15];
  const float* kW  = (const float*)d_in[16]; const float* kb  = (const float*)d_in[17];
  const float* vW  = (const float*)d_in[18]; const float* vb  = (const float*)d_in[19];
  const float* sW  = (const float*)d_in[20]; const float* sb  = (const float*)d_in[21];

  float* out = (float*)d_out;
  float* ws  = (float*)d_ws;

  const long ND = (long)N_ * D_;
  float* h_init = ws;           // region 0
  float* qbuf   = ws + ND;      // region 1
  float* kbuf   = ws + 2 * ND;  // region 2
  float* vbuf   = ws + 3 * ND;  // region 3

  // CSR overlays in region 0 (h_init dead after the projections)
  int* deg  = (int*)h_init;
  int* off  = deg + N_;
  int* cur  = off + N_;
  int* esrc = cur + N_;
  int* bsum = esrc + E_;

  // update-MLP temporaries (regions 1/2 dead after k_attn)
  float* t1 = kbuf;
  float* t2 = qbuf;

  const int g32  = N_ / NT_;            // 3125
  const int gT   = (N_ + 127) / 128;    // 782 (128-node MFMA tiles)

  // --- prep MLP: x -> h_init ---
  gemm_small<F_, 64, true><<<g32, 128, 0, stream>>>(x, pW1, pb1, t1);
  mfma_gemm<64, 128, true,  false><<<gT, 256, 0, stream>>>(t1, pW2, pb2, nullptr, t2);
  mfma_gemm<128,128, false, false><<<gT, 256, 0, stream>>>(t2, pW3, pb3, nullptr, h_init);

  // --- projections ---
  mfma_gemm<128,128, false, false><<<gT, 256, 0, stream>>>(h_init, qW, qb, nullptr, qbuf);
  mfma_gemm<128,128, false, false><<<gT, 256, 0, stream>>>(h_init, kW, kb, nullptr, kbuf);
  mfma_gemm<128,128, false, false><<<gT, 256, 0, stream>>>(h_init, vW, vb, nullptr, vbuf);
  mfma_gemm<128,128, false, false><<<gT, 256, 0, stream>>>(h_init, sW, sb, nullptr, out);

  // --- CSR build (region 0 now free) ---
  k_zero <<<(N_ + 255) / 256, 256, 0, stream>>>(deg);
  k_hist <<<(E_ + 255) / 256, 256, 0, stream>>>(ei, deg);
  k_scan1<<<SCAN_NB, 256, 0, stream>>>(deg, off, bsum);
  k_scan2<<<1, 512, 0, stream>>>(bsum);
  k_scan3<<<SCAN_NB, 256, 0, stream>>>(off, bsum, cur);
  k_fill <<<(E_ + 255) / 256, 256, 0, stream>>>(ei, cur, esrc);

  // --- attention (adds onto skip already in out) ---
  k_attn<<<(N_ + 3) / 4, 256, 0, stream>>>(esrc, off, deg, qbuf, kbuf, vbuf, out);

  // --- update MLP with residual: out = h + mlp(h), h == out ---
  mfma_gemm<128, 64, true,  false><<<gT, 256, 0, stream>>>(out, uW1, ub1, nullptr, t1);
  mfma_gemm<64, 128, true,  false><<<gT, 256, 0, stream>>>(t1,  uW2, ub2, nullptr, t2);
  mfma_gemm<128,128, false, true ><<<gT, 256, 0, stream>>>(t2,  uW3, ub3, out, out);
}